// Round 1
// baseline (3104.482 us; speedup 1.0000x reference)
//
#include <hip/hip_runtime.h>

#define EPSV 1e-5f

// rot90 applied r times CCW (np.rot90 semantics): out[dy][dx] = m[sy][sx]
__device__ __forceinline__ int rotsrc(int r, int dy, int dx, int K) {
  int sy, sx;
  if (r == 0)      { sy = dy;       sx = dx; }
  else if (r == 1) { sy = dx;       sx = K - 1 - dy; }
  else if (r == 2) { sy = K - 1 - dy; sx = K - 1 - dx; }
  else             { sy = K - 1 - dx; sx = dy; }
  return sy * K + sx;
}

// One launch: zero stats (7 layers x 32 floats) + expand all P4 kernels into
// ci-major layout Kt[ci][oc][k*k].
__global__ void prep_kernel(const float* __restrict__ w1, const float* __restrict__ w2,
                            const float* __restrict__ w3, const float* __restrict__ w4,
                            const float* __restrict__ w5, const float* __restrict__ w6,
                            const float* __restrict__ w7,
                            float* __restrict__ Kbase, float* __restrict__ stats) {
  int idx = blockIdx.x * blockDim.x + threadIdx.x;
  if (idx < 224) { stats[idx] = 0.f; return; }
  idx -= 224;
  if (idx < 360) { // lifting kernel: K1[oc=c*4+r][tap] = rot_r(w1[c])[tap]
    int oc = idx / 9, tap = idx % 9;
    int c = oc >> 2, r = oc & 3, dy = tap / 3, dx = tap % 3;
    Kbase[idx] = w1[c * 9 + rotsrc(r, dy, dx, 3)];
    return;
  }
  idx -= 360;
  if (idx < 72000) { // 5 regular->regular 3x3 gconv kernels (w2..w6)
    int l = idx / 14400, i = idx % 14400;
    const float* w = (l == 0) ? w2 : (l == 1) ? w3 : (l == 2) ? w4 : (l == 3) ? w5 : w6;
    int ci = i / 360, rem = i % 360, oc = rem / 9, tap = rem % 9;
    int co = oc >> 2, r = oc & 3, cin = ci >> 2, s = ci & 3;
    int srel = (s - r + 4) & 3;
    int dy = tap / 3, dx = tap % 3;
    // K[co*4+r][cin*4+s][dy][dx] = rot_r(w[co][cin][(s-r)%4])[dy][dx], stored ci-major
    Kbase[(l + 1) * 25600 + i] = w[((co * 10 + cin) * 4 + srel) * 9 + rotsrc(r, dy, dx, 3)];
    return;
  }
  idx -= 72000;
  if (idx < 25600) { // 4x4 gconv kernel (w7)
    int ci = idx / 640, rem = idx % 640, oc = rem / 16, tap = rem % 16;
    int co = oc >> 2, r = oc & 3, cin = ci >> 2, s = ci & 3;
    int srel = (s - r + 4) & 3;
    int dy = tap / 4, dx = tap % 4;
    Kbase[6 * 25600 + idx] = w7[((co * 10 + cin) * 4 + srel) * 16 + rotsrc(r, dy, dx, 4)];
  }
}

// Generic tiled conv. One block = one image x one THxTW output tile x all 40
// output channels. Input tile staged in LDS with BN+ReLU of the PREVIOUS layer
// applied on load (scale/shift recomputed per block from raw sums: cheap).
// Raw conv outputs' per-field sum/sumsq accumulated to `stats` via shuffle
// reduce + 20 atomics/block. POOL variant (layer 2) computes full-res stats,
// then 2x2-max-pools the raw outputs (valid: gamma>0 -> BN monotone).
template<int CIN, int H, int W, int OH, int OW, int TH, int TW, int KS, int PAD,
         bool POOL, bool BN_IN>
__global__ __launch_bounds__(256) void convk(
    const float* __restrict__ in, const float* __restrict__ Kt,
    const float* __restrict__ pstats, const float* __restrict__ pgamma,
    const float* __restrict__ pbeta, float pinvn,
    float* __restrict__ out, float* __restrict__ stats) {
  constexpr int KSQ = KS * KS;
  constexpr int IH = TH + KS - 1, IW = TW + KS - 1, IWP = IW + 1; // +1: bank-conflict pad
  constexpr int NTX = OW / TW, NTY = OH / TH, NT = NTX * NTY;
  __shared__ float tile[CIN * IH * IWP];
  __shared__ float sc[10], sh[10];
  __shared__ float wred[4 * 20];
  const int tid = threadIdx.x;
  const int bid = blockIdx.x;
  const int n = bid / NT, t = bid % NT;
  const int ty = t / NTX, tx = t % NTX;

  if constexpr (BN_IN) {
    if (tid < 10) {
      float mu = pstats[tid] * pinvn;
      float q  = pstats[10 + tid] * pinvn;
      float isd = rsqrtf(q - mu * mu + EPSV);
      float s = pgamma[tid] * isd;
      sc[tid] = s;
      sh[tid] = pbeta[tid] - mu * s;
    }
    __syncthreads();
  }

  // ---- stage input tile (halo + zero padding), BN+ReLU on load ----
  const float* inb = in + (long)n * CIN * H * W;
  for (int idx = tid; idx < CIN * IH * IW; idx += blockDim.x) {
    int ci = idx / (IH * IW), rem = idx % (IH * IW), iy = rem / IW, ix = rem % IW;
    int gy = ty * TH + iy - PAD, gx = tx * TW + ix - PAD;
    float v = 0.f;
    if (gy >= 0 && gy < H && gx >= 0 && gx < W) {
      v = inb[(ci * H + gy) * W + gx];
      if constexpr (BN_IN) v = fmaxf(0.f, fmaf(v, sc[ci >> 2], sh[ci >> 2]));
    }
    tile[ci * (IH * IWP) + iy * IWP + ix] = v;
  }
  __syncthreads();

  // ---- compute: one pixel per thread, all 40 output channels ----
  float acc[40];
#pragma unroll
  for (int i = 0; i < 40; ++i) acc[i] = 0.f;
  const bool active = tid < TH * TW;
  if (active) {
    const int y = tid / TW, x = tid % TW;
#pragma unroll 2
    for (int ci = 0; ci < CIN; ++ci) {
      float tv[KSQ];
#pragma unroll
      for (int k = 0; k < KSQ; ++k)
        tv[k] = tile[ci * (IH * IWP) + (y + k / KS) * IWP + (x + k % KS)];
      const float* __restrict__ wp = Kt + ci * (40 * KSQ); // uniform -> scalar loads
#pragma unroll
      for (int oc = 0; oc < 40; ++oc) {
        float a = acc[oc];
#pragma unroll
        for (int k = 0; k < KSQ; ++k) a = fmaf(tv[k], wp[oc * KSQ + k], a);
        acc[oc] = a;
      }
    }
  }

  // ---- fused BN stats: per-field sum & sumsq of raw outputs ----
  {
    float s[10], q[10];
#pragma unroll
    for (int f = 0; f < 10; ++f) {
      float a0 = acc[4 * f], a1 = acc[4 * f + 1], a2 = acc[4 * f + 2], a3 = acc[4 * f + 3];
      s[f] = a0 + a1 + a2 + a3;
      q[f] = a0 * a0 + a1 * a1 + a2 * a2 + a3 * a3;
    }
#pragma unroll
    for (int f = 0; f < 10; ++f) {
#pragma unroll
      for (int off = 32; off > 0; off >>= 1) {
        s[f] += __shfl_xor(s[f], off, 64);
        q[f] += __shfl_xor(q[f], off, 64);
      }
    }
    const int wv = tid >> 6, lane = tid & 63;
    if (lane == 0) {
#pragma unroll
      for (int f = 0; f < 10; ++f) {
        wred[wv * 20 + f] = s[f];
        wred[wv * 20 + 10 + f] = q[f];
      }
    }
    __syncthreads();
    const int nw = blockDim.x >> 6;
    if (tid < 20) {
      float v = 0.f;
      for (int w = 0; w < nw; ++w) v += wred[w * 20 + tid];
      atomicAdd(&stats[tid], v);
    }
  }

  // ---- write raw output (or 2x2-max-pooled raw output) ----
  if constexpr (!POOL) {
    if (active) {
      const int y = tid / TW, x = tid % TW;
      const int oy = ty * TH + y, ox = tx * TW + x;
      float* ob = out + (long)n * 40 * OH * OW;
#pragma unroll
      for (int oc = 0; oc < 40; ++oc) ob[(oc * OH + oy) * OW + ox] = acc[oc];
    }
  } else {
    __syncthreads();            // all tile reads done -> safe to reuse as staging
    float* pbuf = tile;         // 40*TH*TW <= CIN*IH*IWP
    if (active) {
#pragma unroll
      for (int oc = 0; oc < 40; ++oc) pbuf[oc * (TH * TW) + tid] = acc[oc];
    }
    __syncthreads();
    constexpr int PH = TH / 2, PW = TW / 2, POH = OH / 2, POW = OW / 2;
    if (tid < PH * PW) {
      const int py = tid / PW, px = tid % PW;
      const int base = (2 * py) * TW + 2 * px;
#pragma unroll
      for (int oc = 0; oc < 40; ++oc) {
        const float* pb = pbuf + oc * (TH * TW);
        float m = fmaxf(fmaxf(pb[base], pb[base + 1]),
                        fmaxf(pb[base + TW], pb[base + TW + 1]));
        out[((long)n * 40 + oc) * POH * POW + (ty * PH + py) * POW + (tx * PW + px)] = m;
      }
    }
  }
}

// BN+ReLU(layer7) -> orientation max -> FC. One block per image.
__global__ __launch_bounds__(256) void head_kernel(
    const float* __restrict__ raw, const float* __restrict__ stats7,
    const float* __restrict__ gs, const float* __restrict__ bs,
    const float* __restrict__ wfc, const float* __restrict__ bfc,
    float* __restrict__ out, float invn) {
  __shared__ float sc[10], sh[10];
  __shared__ float m[1210];
  __shared__ float red[40];
  const int tid = threadIdx.x, n = blockIdx.x;
  if (tid < 10) {
    float mu = stats7[tid] * invn, q = stats7[10 + tid] * invn;
    float isd = rsqrtf(q - mu * mu + EPSV);
    float s = gs[tid] * isd;
    sc[tid] = s;
    sh[tid] = bs[tid] - mu * s;
  }
  __syncthreads();
  const float* rb = raw + (long)n * 40 * 121;
  for (int idx = tid; idx < 1210; idx += blockDim.x) {
    int c = idx / 121, p = idx % 121;
    float s = sc[c], h = sh[c];
    float v0 = fmaxf(0.f, fmaf(rb[(c * 4 + 0) * 121 + p], s, h));
    float v1 = fmaxf(0.f, fmaf(rb[(c * 4 + 1) * 121 + p], s, h));
    float v2 = fmaxf(0.f, fmaf(rb[(c * 4 + 2) * 121 + p], s, h));
    float v3 = fmaxf(0.f, fmaf(rb[(c * 4 + 3) * 121 + p], s, h));
    m[idx] = fmaxf(fmaxf(v0, v1), fmaxf(v2, v3));
  }
  __syncthreads();
  const int wv = tid >> 6, lane = tid & 63;
  for (int k = 0; k < 10; ++k) {
    float p = 0.f;
    for (int j = tid; j < 1210; j += blockDim.x) p += m[j] * wfc[k * 1210 + j];
#pragma unroll
    for (int off = 32; off > 0; off >>= 1) p += __shfl_xor(p, off, 64);
    if (lane == 0) red[k * 4 + wv] = p;
  }
  __syncthreads();
  if (tid < 10)
    out[n * 10 + tid] = bfc[tid] + red[tid * 4] + red[tid * 4 + 1] +
                        red[tid * 4 + 2] + red[tid * 4 + 3];
}

extern "C" void kernel_launch(void* const* d_in, const int* in_sizes, int n_in,
                              void* d_out, int out_size, void* d_ws, size_t ws_size,
                              hipStream_t stream) {
  const float* x   = (const float*)d_in[0];
  const float* w1  = (const float*)d_in[1];
  const float* w2  = (const float*)d_in[2];
  const float* w3  = (const float*)d_in[3];
  const float* w4  = (const float*)d_in[4];
  const float* w5  = (const float*)d_in[5];
  const float* w6  = (const float*)d_in[6];
  const float* w7  = (const float*)d_in[7];
  const float* g1  = (const float*)d_in[8];
  const float* b1  = (const float*)d_in[9];
  const float* g2  = (const float*)d_in[10];
  const float* b2  = (const float*)d_in[11];
  const float* gs  = (const float*)d_in[12];
  const float* bs  = (const float*)d_in[13];
  const float* wfc = (const float*)d_in[14];
  const float* bfc = (const float*)d_in[15];

  float* ws = (float*)d_ws;
  // Workspace map (floats). Total 40,320,224 floats = 161.3 MB.
  float* A    = ws;                 // conv1 raw out [1024,40,28,28] (32,112,640)
  float* B14  = ws + 32112640L;     // pooled conv2 raw [1024,40,14,14] (8,028,160)
  float* C14  = ws;                 // ping (A dead after conv2)
  float* D14  = ws + 8028160L;      // pong (inside A region)
  float* B11  = B14;                // conv7 raw out [1024,40,11,11] (B14 dead)
  float* K    = ws + 40140800L;     // 7 kernel slots x 25600 floats
  float* stats = K + 7 * 25600L;    // 7 layers x 32 floats (sum[10], sumsq[10])

  const float invn28 = 1.f / 3211264.f;  // B*G*28*28
  const float invn14 = 1.f / 802816.f;   // B*G*14*14
  const float invn11 = 1.f / 495616.f;   // B*G*11*11

  prep_kernel<<<384, 256, 0, stream>>>(w1, w2, w3, w4, w5, w6, w7, K, stats);

  // conv1 (lift, Cin=1), raw -> A, stats[0]
  convk<1, 28, 28, 28, 28, 14, 14, 3, 1, false, false><<<4096, 256, 0, stream>>>(
      x, K, nullptr, nullptr, nullptr, 0.f, A, stats);
  // conv2: BN1 on load, full-res stats[1], pooled raw -> B14
  convk<40, 28, 28, 28, 28, 14, 14, 3, 1, true, true><<<4096, 256, 0, stream>>>(
      A, K + 25600, stats, g1, b1, invn28, B14, stats + 32);
  // conv3..conv6: 14x14, BN of previous layer on load
  convk<40, 14, 14, 14, 14, 14, 14, 3, 1, false, true><<<1024, 256, 0, stream>>>(
      B14, K + 2 * 25600, stats + 32, g2, b2, invn28, C14, stats + 64);
  convk<40, 14, 14, 14, 14, 14, 14, 3, 1, false, true><<<1024, 256, 0, stream>>>(
      C14, K + 3 * 25600, stats + 64, gs, bs, invn14, D14, stats + 96);
  convk<40, 14, 14, 14, 14, 14, 14, 3, 1, false, true><<<1024, 256, 0, stream>>>(
      D14, K + 4 * 25600, stats + 96, gs, bs, invn14, C14, stats + 128);
  convk<40, 14, 14, 14, 14, 14, 14, 3, 1, false, true><<<1024, 256, 0, stream>>>(
      C14, K + 5 * 25600, stats + 128, gs, bs, invn14, D14, stats + 160);
  // conv7: 4x4 valid, 14->11, block of 128 (121 active)
  convk<40, 14, 14, 11, 11, 11, 11, 4, 0, false, true><<<1024, 128, 0, stream>>>(
      D14, K + 6 * 25600, stats + 160, gs, bs, invn14, B11, stats + 192);
  // head: BN7 + ReLU + orientation-max + FC
  head_kernel<<<1024, 256, 0, stream>>>(B11, stats + 192, gs, bs, wfc, bfc,
                                        (float*)d_out, invn11);
}

// Round 2
// 1276.828 us; speedup vs baseline: 2.4314x; 2.4314x over previous
//
#include <hip/hip_runtime.h>

#define EPSV 1e-5f

// rot90 applied r times CCW (np.rot90 semantics): out[dy][dx] = m[sy][sx]
__device__ __forceinline__ int rotsrc(int r, int dy, int dx, int K) {
  int sy, sx;
  if (r == 0)      { sy = dy;       sx = dx; }
  else if (r == 1) { sy = dx;       sx = K - 1 - dy; }
  else if (r == 2) { sy = K - 1 - dy; sx = K - 1 - dx; }
  else             { sy = K - 1 - dx; sx = dy; }
  return sy * K + sx;
}

// Zero stats + expand all P4 kernels into [ci][tap][oc] layout (oc fastest,
// 40 contiguous floats -> ocg*8 offsets are 32B aligned for float4 loads).
__global__ void prep_kernel(const float* __restrict__ w1, const float* __restrict__ w2,
                            const float* __restrict__ w3, const float* __restrict__ w4,
                            const float* __restrict__ w5, const float* __restrict__ w6,
                            const float* __restrict__ w7,
                            float* __restrict__ Kbase, float* __restrict__ stats) {
  int idx = blockIdx.x * blockDim.x + threadIdx.x;
  if (idx < 224) { stats[idx] = 0.f; return; }
  idx -= 224;
  if (idx < 360) { // lifting kernel: K1[tap][oc] = rot_r(w1[c])[tap]
    int tap = idx / 40, oc = idx % 40;
    int c = oc >> 2, r = oc & 3, dy = tap / 3, dx = tap % 3;
    Kbase[idx] = w1[c * 9 + rotsrc(r, dy, dx, 3)];
    return;
  }
  idx -= 360;
  if (idx < 72000) { // 5 regular->regular 3x3 gconv kernels (w2..w6), [ci][tap][oc]
    int l = idx / 14400, i = idx % 14400;
    const float* w = (l == 0) ? w2 : (l == 1) ? w3 : (l == 2) ? w4 : (l == 3) ? w5 : w6;
    int ci = i / 360, rem = i % 360, tap = rem / 40, oc = rem % 40;
    int co = oc >> 2, r = oc & 3, cin = ci >> 2, s = ci & 3;
    int srel = (s - r + 4) & 3;
    int dy = tap / 3, dx = tap % 3;
    Kbase[(l + 1) * 25600 + i] = w[((co * 10 + cin) * 4 + srel) * 9 + rotsrc(r, dy, dx, 3)];
    return;
  }
  idx -= 72000;
  if (idx < 25600) { // 4x4 gconv kernel (w7), [ci][tap][oc]
    int ci = idx / 640, rem = idx % 640, tap = rem / 40, oc = rem % 40;
    int co = oc >> 2, r = oc & 3, cin = ci >> 2, s = ci & 3;
    int srel = (s - r + 4) & 3;
    int dy = tap / 4, dx = tap % 4;
    Kbase[6 * 25600 + idx] = w7[((co * 10 + cin) * 4 + srel) * 16 + rotsrc(r, dy, dx, 4)];
  }
}

// Register-tiled conv. Thread = (oc-group of 8) x (2x2 output pixel block).
// Input tile in LDS (16x18 padded rows per ci); weights streamed from global
// ([ci][tap][oc] layout) as 2x float4 per tap -> VGPRs, reused over 4 pixels.
// Per ci: FMA 576 cyc/wave vs ~90 LDS cyc -> VALU-bound.
// BN+ReLU of previous layer applied on the LDS staging load. Per-field BN
// stats of the raw outputs accumulated via LDS float atomics, then one
// global atomic per stat. POOL: 2x2 thread block == one pooling window,
// pooled in registers (valid: gamma>0 -> BN monotone, pool commutes).
template<int CIN, int H, int W, int OH, int OW, int KS, int PAD,
         int NTX, int NTY, int PBY, int PBX, bool POOL, bool BN_IN, int BDIM>
__global__ __launch_bounds__(BDIM) void convk2(
    const float* __restrict__ in, const float* __restrict__ Kt,
    const float* __restrict__ pstats, const float* __restrict__ pgamma,
    const float* __restrict__ pbeta, float pinvn,
    float* __restrict__ out, float* __restrict__ stats) {
  constexpr int KSQ = KS * KS;
  constexpr int PS = KS + 1;                 // patch edge (2 px + K-1)
  constexpr int TIH = 16, TIW = 16, TIWP = 18;
  constexpr int TH = 2 * PBY, TW = 2 * PBX;  // output tile dims
  constexpr int NPB = PBY * PBX;
  constexpr int NACT = 5 * NPB;              // 5 oc-groups of 8
  constexpr int NT = NTX * NTY;
  constexpr bool MASK = (OH != NTY * TH) || (OW != NTX * TW);
  __shared__ float tile[CIN * TIH * TIWP];
  __shared__ float sc[10], sh[10];
  __shared__ float sstat[20];
  const int tid = threadIdx.x;
  const int bid = blockIdx.x;
  const int n = bid / NT, t = bid % NT;
  const int ty = t / NTX, tx = t % NTX;

  if (tid < 20) sstat[tid] = 0.f;
  if constexpr (BN_IN) {
    if (tid < 10) {
      float mu = pstats[tid] * pinvn;
      float q  = pstats[10 + tid] * pinvn;
      float isd = rsqrtf(q - mu * mu + EPSV);
      float s = pgamma[tid] * isd;
      sc[tid] = s;
      sh[tid] = pbeta[tid] - mu * s;
    }
  }
  __syncthreads();

  // ---- stage input tile (halo + zero pad), BN+ReLU of prev layer on load ----
  const float* inb = in + (long)n * CIN * H * W;
  for (int idx = tid; idx < CIN * TIH * TIW; idx += BDIM) {
    int ci = idx >> 8, rem = idx & 255, iy = rem >> 4, ix = rem & 15;
    int gy = ty * TH + iy - PAD, gx = tx * TW + ix - PAD;
    float v = 0.f;
    if (gy >= 0 && gy < H && gx >= 0 && gx < W) {
      v = inb[(ci * H + gy) * W + gx];
      if constexpr (BN_IN) v = fmaxf(0.f, fmaf(v, sc[ci >> 2], sh[ci >> 2]));
    }
    tile[ci * (TIH * TIWP) + iy * TIWP + ix] = v;
  }
  __syncthreads();

  const bool active = tid < NACT;
  const int wi = active ? tid : 0;           // clamp: inactive lanes duplicate
  const int ocg = wi / NPB, pxg = wi % NPB;  // thread 0 (no OOB), masked below
  const int Y = pxg / PBX, X = pxg % PBX;

  float acc[32];                             // [oc 0..7][px 0..3 = j*2+i]
#pragma unroll
  for (int i = 0; i < 32; ++i) acc[i] = 0.f;

  const float* tb0 = &tile[(2 * Y) * TIWP + 2 * X];
  const float* wb0 = Kt + ocg * 8;
  for (int ci = 0; ci < CIN; ++ci) {
    // input patch PSxPS from LDS (aligned float2 reads; even addrs)
    float patch[PS * PS];
    const float* tb = tb0 + ci * (TIH * TIWP);
#pragma unroll
    for (int p = 0; p < PS; ++p) {
#pragma unroll
      for (int c2 = 0; c2 + 1 < PS; c2 += 2) {
        float2 v = *(const float2*)&tb[p * TIWP + c2];
        patch[p * PS + c2] = v.x;
        patch[p * PS + c2 + 1] = v.y;
      }
      if constexpr (PS & 1) patch[p * PS + PS - 1] = tb[p * TIWP + PS - 1];
    }
    const float* wb = wb0 + ci * (KSQ * 40);
#pragma unroll
    for (int tap = 0; tap < KSQ; ++tap) {
      const float4 wa = *(const float4*)&wb[tap * 40];
      const float4 wc = *(const float4*)&wb[tap * 40 + 4];
      const float wv[8] = {wa.x, wa.y, wa.z, wa.w, wc.x, wc.y, wc.z, wc.w};
      const int dy = tap / KS, dx = tap % KS;
#pragma unroll
      for (int o = 0; o < 8; ++o)
#pragma unroll
        for (int j = 0; j < 2; ++j)
#pragma unroll
          for (int i = 0; i < 2; ++i)
            acc[o * 4 + j * 2 + i] =
                fmaf(wv[o], patch[(j + dy) * PS + (i + dx)], acc[o * 4 + j * 2 + i]);
    }
  }

  // ---- output coords + validity masks ----
  const int oy0 = ty * TH + 2 * Y, ox0 = tx * TW + 2 * X;
  bool pv[4];
#pragma unroll
  for (int j = 0; j < 2; ++j)
#pragma unroll
    for (int i = 0; i < 2; ++i)
      pv[j * 2 + i] = !MASK || (oy0 + j < OH && ox0 + i < OW);

  // ---- BN stats: 8 oc = fields 2*ocg, 2*ocg+1 ----
  if (active) {
    float s0 = 0.f, q0 = 0.f, s1 = 0.f, q1 = 0.f;
#pragma unroll
    for (int o = 0; o < 8; ++o)
#pragma unroll
      for (int p = 0; p < 4; ++p) {
        if (pv[p]) {
          float v = acc[o * 4 + p];
          if (o < 4) { s0 += v; q0 += v * v; }
          else       { s1 += v; q1 += v * v; }
        }
      }
    atomicAdd(&sstat[2 * ocg], s0);
    atomicAdd(&sstat[2 * ocg + 1], s1);
    atomicAdd(&sstat[10 + 2 * ocg], q0);
    atomicAdd(&sstat[10 + 2 * ocg + 1], q1);
  }

  // ---- write raw output (or 2x2 max-pooled raw) ----
  if (active) {
    if constexpr (POOL) {
      constexpr int POH = OH / 2, POW = OW / 2;
      float* ob = out + (long)n * 40 * POH * POW;
      const int py = ty * PBY + Y, px = tx * PBX + X;
#pragma unroll
      for (int o = 0; o < 8; ++o) {
        const int oc = ocg * 8 + o;
        float m = fmaxf(fmaxf(acc[o * 4], acc[o * 4 + 1]),
                        fmaxf(acc[o * 4 + 2], acc[o * 4 + 3]));
        ob[(oc * POH + py) * POW + px] = m;
      }
    } else {
      float* ob = out + (long)n * 40 * OH * OW;
#pragma unroll
      for (int o = 0; o < 8; ++o) {
        const int oc = ocg * 8 + o;
#pragma unroll
        for (int j = 0; j < 2; ++j) {
          if constexpr (!MASK) {
            float2 v = make_float2(acc[o * 4 + j * 2], acc[o * 4 + j * 2 + 1]);
            *(float2*)&ob[(oc * OH + oy0 + j) * OW + ox0] = v;
          } else {
            if (oy0 + j < OH) {
              if (ox0 < OW)     ob[(oc * OH + oy0 + j) * OW + ox0]     = acc[o * 4 + j * 2];
              if (ox0 + 1 < OW) ob[(oc * OH + oy0 + j) * OW + ox0 + 1] = acc[o * 4 + j * 2 + 1];
            }
          }
        }
      }
    }
  }
  __syncthreads();
  if (tid < 20) atomicAdd(&stats[tid], sstat[tid]);
}

// BN+ReLU(layer7) -> orientation max -> FC. One block per image.
__global__ __launch_bounds__(256) void head_kernel(
    const float* __restrict__ raw, const float* __restrict__ stats7,
    const float* __restrict__ gs, const float* __restrict__ bs,
    const float* __restrict__ wfc, const float* __restrict__ bfc,
    float* __restrict__ out, float invn) {
  __shared__ float sc[10], sh[10];
  __shared__ float m[1210];
  __shared__ float red[40];
  const int tid = threadIdx.x, n = blockIdx.x;
  if (tid < 10) {
    float mu = stats7[tid] * invn, q = stats7[10 + tid] * invn;
    float isd = rsqrtf(q - mu * mu + EPSV);
    float s = gs[tid] * isd;
    sc[tid] = s;
    sh[tid] = bs[tid] - mu * s;
  }
  __syncthreads();
  const float* rb = raw + (long)n * 40 * 121;
  for (int idx = tid; idx < 1210; idx += blockDim.x) {
    int c = idx / 121, p = idx % 121;
    float s = sc[c], h = sh[c];
    float v0 = fmaxf(0.f, fmaf(rb[(c * 4 + 0) * 121 + p], s, h));
    float v1 = fmaxf(0.f, fmaf(rb[(c * 4 + 1) * 121 + p], s, h));
    float v2 = fmaxf(0.f, fmaf(rb[(c * 4 + 2) * 121 + p], s, h));
    float v3 = fmaxf(0.f, fmaf(rb[(c * 4 + 3) * 121 + p], s, h));
    m[idx] = fmaxf(fmaxf(v0, v1), fmaxf(v2, v3));
  }
  __syncthreads();
  const int wv = tid >> 6, lane = tid & 63;
  for (int k = 0; k < 10; ++k) {
    float p = 0.f;
    for (int j = tid; j < 1210; j += blockDim.x) p += m[j] * wfc[k * 1210 + j];
#pragma unroll
    for (int off = 32; off > 0; off >>= 1) p += __shfl_xor(p, off, 64);
    if (lane == 0) red[k * 4 + wv] = p;
  }
  __syncthreads();
  if (tid < 10)
    out[n * 10 + tid] = bfc[tid] + red[tid * 4] + red[tid * 4 + 1] +
                        red[tid * 4 + 2] + red[tid * 4 + 3];
}

extern "C" void kernel_launch(void* const* d_in, const int* in_sizes, int n_in,
                              void* d_out, int out_size, void* d_ws, size_t ws_size,
                              hipStream_t stream) {
  const float* x   = (const float*)d_in[0];
  const float* w1  = (const float*)d_in[1];
  const float* w2  = (const float*)d_in[2];
  const float* w3  = (const float*)d_in[3];
  const float* w4  = (const float*)d_in[4];
  const float* w5  = (const float*)d_in[5];
  const float* w6  = (const float*)d_in[6];
  const float* w7  = (const float*)d_in[7];
  const float* g1  = (const float*)d_in[8];
  const float* b1  = (const float*)d_in[9];
  const float* g2  = (const float*)d_in[10];
  const float* b2  = (const float*)d_in[11];
  const float* gs  = (const float*)d_in[12];
  const float* bs  = (const float*)d_in[13];
  const float* wfc = (const float*)d_in[14];
  const float* bfc = (const float*)d_in[15];

  float* ws = (float*)d_ws;
  // Workspace map (floats). Total ~161.3 MB.
  float* A    = ws;                 // conv1 raw out [1024,40,28,28] (32,112,640)
  float* B14  = ws + 32112640L;     // pooled conv2 raw [1024,40,14,14] (8,028,160)
  float* C14  = ws;                 // ping (A dead after conv2)
  float* D14  = ws + 8028160L;      // pong (inside A region)
  float* B11  = B14;                // conv7 raw out [1024,40,11,11] (B14 dead)
  float* K    = ws + 40140800L;     // 7 kernel slots x 25600 floats
  float* stats = K + 7 * 25600L;    // 7 layers x 32 floats (sum[10], sumsq[10])

  const float invn28 = 1.f / 3211264.f;  // B*G*28*28
  const float invn14 = 1.f / 802816.f;   // B*G*14*14
  const float invn11 = 1.f / 495616.f;   // B*G*11*11

  prep_kernel<<<384, 256, 0, stream>>>(w1, w2, w3, w4, w5, w6, w7, K, stats);

  // conv1 (lift, Cin=1): raw -> A, stats[0]
  convk2<1, 28, 28, 28, 28, 3, 1, 2, 2, 7, 7, false, false, 256>
      <<<4096, 256, 0, stream>>>(x, K, nullptr, nullptr, nullptr, 0.f, A, stats);
  // conv2: BN1 on load, full-res stats[1], pooled raw -> B14
  convk2<40, 28, 28, 28, 28, 3, 1, 2, 2, 7, 7, true, true, 256>
      <<<4096, 256, 0, stream>>>(A, K + 25600, stats, g1, b1, invn28, B14, stats + 32);
  // conv3..conv6 at 14x14
  convk2<40, 14, 14, 14, 14, 3, 1, 1, 1, 7, 7, false, true, 256>
      <<<1024, 256, 0, stream>>>(B14, K + 2 * 25600, stats + 32, g2, b2, invn28, C14, stats + 64);
  convk2<40, 14, 14, 14, 14, 3, 1, 1, 1, 7, 7, false, true, 256>
      <<<1024, 256, 0, stream>>>(C14, K + 3 * 25600, stats + 64, gs, bs, invn14, D14, stats + 96);
  convk2<40, 14, 14, 14, 14, 3, 1, 1, 1, 7, 7, false, true, 256>
      <<<1024, 256, 0, stream>>>(D14, K + 4 * 25600, stats + 96, gs, bs, invn14, C14, stats + 128);
  convk2<40, 14, 14, 14, 14, 3, 1, 1, 1, 7, 7, false, true, 256>
      <<<1024, 256, 0, stream>>>(C14, K + 5 * 25600, stats + 128, gs, bs, invn14, D14, stats + 160);
  // conv7: 4x4 valid, 14->11 (12x12 computed, masked to 11x11)
  convk2<40, 14, 14, 11, 11, 4, 0, 1, 1, 6, 6, false, true, 192>
      <<<1024, 192, 0, stream>>>(D14, K + 6 * 25600, stats + 160, gs, bs, invn14, B11, stats + 192);
  // head: BN7 + ReLU + orientation-max + FC
  head_kernel<<<1024, 256, 0, stream>>>(B11, stats + 192, gs, bs, wfc, bfc,
                                        (float*)d_out, invn11);
}

// Round 3
// 711.273 us; speedup vs baseline: 4.3647x; 1.7951x over previous
//
#include <hip/hip_runtime.h>

#define EPSV 1e-5f

typedef __bf16 v8bf __attribute__((ext_vector_type(8)));
typedef float v4f __attribute__((ext_vector_type(4)));

// rot90 applied r times CCW (np.rot90 semantics): out[dy][dx] = m[sy][sx]
__device__ __forceinline__ int rotsrc(int r, int dy, int dx, int K) {
  int sy, sx;
  if (r == 0)      { sy = dy;       sx = dx; }
  else if (r == 1) { sy = dx;       sx = K - 1 - dy; }
  else if (r == 2) { sy = K - 1 - dy; sx = K - 1 - dx; }
  else             { sy = K - 1 - dx; sx = dy; }
  return sy * K + sx;
}

// P4 weight expansion: full kernel value for output channel oc, k-group g,
// within-group index j. g = (tap, ci-group-of-8): tap = g/5, ci = (g%5)*8+j.
__device__ __forceinline__ float gw_val(const float* __restrict__ w, int oc, int g,
                                        int j, int KS) {
  int tap = g / 5, cig = g % 5, ci = cig * 8 + j;
  int co = oc >> 2, r = oc & 3, cin = ci >> 2, s = ci & 3;
  int srel = (s - r) & 3;
  return w[((co * 10 + cin) * 4 + srel) * (KS * KS) + rotsrc(r, tap / KS, tap % KS, KS)];
}

// Zero stats + conv1 float table [tap][oc] + MFMA bf16 weight tables.
// MFMA layout per layer: [mt(3)][c(NC)][q(4)][ocl(16)][j(8)] so a lane
// (quad, m) reads A[m=oc][k=quad*8+j] as one contiguous 16B load.
__global__ void prep_kernel(const float* __restrict__ w1, const float* __restrict__ w2,
                            const float* __restrict__ w3, const float* __restrict__ w4,
                            const float* __restrict__ w5, const float* __restrict__ w6,
                            const float* __restrict__ w7,
                            float* __restrict__ K1, __bf16* __restrict__ Wb,
                            float* __restrict__ stats) {
  int idx = blockIdx.x * blockDim.x + threadIdx.x;
  if (idx < 224) { stats[idx] = 0.f; return; }
  idx -= 224;
  if (idx < 360) { // lifting kernel [tap][oc]
    int tap = idx / 40, oc = idx % 40;
    int c = oc >> 2, r = oc & 3;
    K1[idx] = w1[c * 9 + rotsrc(r, tap / 3, tap % 3, 3)];
    return;
  }
  idx -= 360;
  if (idx < 92160) { // conv2..conv6: 5 layers x [3][12][4][16][8]
    int l = idx / 18432, r0 = idx % 18432;
    const float* w = (l == 0) ? w2 : (l == 1) ? w3 : (l == 2) ? w4 : (l == 3) ? w5 : w6;
    int mt = r0 / 6144, r1 = r0 % 6144;
    int c = r1 / 512, r2 = r1 % 512;
    int q = r2 / 128, r3 = r2 % 128;
    int ocl = r3 / 8, j = r3 % 8;
    int oc = mt * 16 + ocl, g = c * 4 + q;
    float val = 0.f;
    if (oc < 40 && g < 45) val = gw_val(w, oc, g, j, 3);
    Wb[idx] = (__bf16)val;
    return;
  }
  idx -= 92160;
  if (idx < 30720) { // conv7: [3][20][4][16][8]
    int mt = idx / 10240, r1 = idx % 10240;
    int c = r1 / 512, r2 = r1 % 512;
    int q = r2 / 128, r3 = r2 % 128;
    int ocl = r3 / 8, j = r3 % 8;
    int oc = mt * 16 + ocl, g = c * 4 + q; // g < 80 always valid
    float val = 0.f;
    if (oc < 40) val = gw_val(w7, oc, g, j, 4);
    Wb[92160 + idx] = (__bf16)val;
  }
}

// ---------------- conv1: fp32 register-tiled (CIN=1, cheap) ----------------
template<int CIN, int H, int W, int OH, int OW, int KS, int PAD,
         int NTX, int NTY, int PBY, int PBX, bool POOL, bool BN_IN, int BDIM>
__global__ __launch_bounds__(BDIM) void convk2(
    const float* __restrict__ in, const float* __restrict__ Kt,
    const float* __restrict__ pstats, const float* __restrict__ pgamma,
    const float* __restrict__ pbeta, float pinvn,
    float* __restrict__ out, float* __restrict__ stats) {
  constexpr int KSQ = KS * KS;
  constexpr int PS = KS + 1;
  constexpr int TIH = 16, TIW = 16, TIWP = 18;
  constexpr int TH = 2 * PBY, TW = 2 * PBX;
  constexpr int NPB = PBY * PBX;
  constexpr int NACT = 5 * NPB;
  constexpr int NT = NTX * NTY;
  constexpr bool MASK = (OH != NTY * TH) || (OW != NTX * TW);
  __shared__ float tile[CIN * TIH * TIWP];
  __shared__ float sc[10], sh[10];
  __shared__ float sstat[20];
  const int tid = threadIdx.x;
  const int bid = blockIdx.x;
  const int n = bid / NT, t = bid % NT;
  const int ty = t / NTX, tx = t % NTX;

  if (tid < 20) sstat[tid] = 0.f;
  if constexpr (BN_IN) {
    if (tid >= 32 && tid < 42) {
      int f = tid - 32;
      float mu = pstats[f] * pinvn, q = pstats[10 + f] * pinvn;
      float isd = rsqrtf(q - mu * mu + EPSV);
      float s = pgamma[f] * isd;
      sc[f] = s; sh[f] = pbeta[f] - mu * s;
    }
  }
  __syncthreads();

  const float* inb = in + (long)n * CIN * H * W;
  for (int idx = tid; idx < CIN * TIH * TIW; idx += BDIM) {
    int ci = idx >> 8, rem = idx & 255, iy = rem >> 4, ix = rem & 15;
    int gy = ty * TH + iy - PAD, gx = tx * TW + ix - PAD;
    float v = 0.f;
    if (gy >= 0 && gy < H && gx >= 0 && gx < W) {
      v = inb[(ci * H + gy) * W + gx];
      if constexpr (BN_IN) v = fmaxf(0.f, fmaf(v, sc[ci >> 2], sh[ci >> 2]));
    }
    tile[ci * (TIH * TIWP) + iy * TIWP + ix] = v;
  }
  __syncthreads();

  const bool active = tid < NACT;
  const int wi = active ? tid : 0;
  const int ocg = wi / NPB, pxg = wi % NPB;
  const int Y = pxg / PBX, X = pxg % PBX;

  float acc[32];
#pragma unroll
  for (int i = 0; i < 32; ++i) acc[i] = 0.f;

  const float* tb0 = &tile[(2 * Y) * TIWP + 2 * X];
  const float* wb0 = Kt + ocg * 8;
  for (int ci = 0; ci < CIN; ++ci) {
    float patch[PS * PS];
    const float* tb = tb0 + ci * (TIH * TIWP);
#pragma unroll
    for (int p = 0; p < PS; ++p) {
#pragma unroll
      for (int c2 = 0; c2 + 1 < PS; c2 += 2) {
        float2 v = *(const float2*)&tb[p * TIWP + c2];
        patch[p * PS + c2] = v.x;
        patch[p * PS + c2 + 1] = v.y;
      }
      if constexpr (PS & 1) patch[p * PS + PS - 1] = tb[p * TIWP + PS - 1];
    }
    const float* wb = wb0 + ci * (KSQ * 40);
#pragma unroll
    for (int tap = 0; tap < KSQ; ++tap) {
      const float4 wa = *(const float4*)&wb[tap * 40];
      const float4 wc = *(const float4*)&wb[tap * 40 + 4];
      const float wv[8] = {wa.x, wa.y, wa.z, wa.w, wc.x, wc.y, wc.z, wc.w};
      const int dy = tap / KS, dx = tap % KS;
#pragma unroll
      for (int o = 0; o < 8; ++o)
#pragma unroll
        for (int j = 0; j < 2; ++j)
#pragma unroll
          for (int i = 0; i < 2; ++i)
            acc[o * 4 + j * 2 + i] =
                fmaf(wv[o], patch[(j + dy) * PS + (i + dx)], acc[o * 4 + j * 2 + i]);
    }
  }

  const int oy0 = ty * TH + 2 * Y, ox0 = tx * TW + 2 * X;
  bool pv[4];
#pragma unroll
  for (int j = 0; j < 2; ++j)
#pragma unroll
    for (int i = 0; i < 2; ++i)
      pv[j * 2 + i] = !MASK || (oy0 + j < OH && ox0 + i < OW);

  if (active) {
    float s0 = 0.f, q0 = 0.f, s1 = 0.f, q1 = 0.f;
#pragma unroll
    for (int o = 0; o < 8; ++o)
#pragma unroll
      for (int p = 0; p < 4; ++p) {
        if (pv[p]) {
          float v = acc[o * 4 + p];
          if (o < 4) { s0 += v; q0 += v * v; }
          else       { s1 += v; q1 += v * v; }
        }
      }
    atomicAdd(&sstat[2 * ocg], s0);
    atomicAdd(&sstat[2 * ocg + 1], s1);
    atomicAdd(&sstat[10 + 2 * ocg], q0);
    atomicAdd(&sstat[10 + 2 * ocg + 1], q1);
  }

  if (active) {
    float* ob = out + (long)n * 40 * OH * OW;
#pragma unroll
    for (int o = 0; o < 8; ++o) {
      const int oc = ocg * 8 + o;
#pragma unroll
      for (int j = 0; j < 2; ++j) {
        if constexpr (!MASK) {
          float2 v = make_float2(acc[o * 4 + j * 2], acc[o * 4 + j * 2 + 1]);
          *(float2*)&ob[(oc * OH + oy0 + j) * OW + ox0] = v;
        } else {
          if (oy0 + j < OH) {
            if (ox0 < OW)     ob[(oc * OH + oy0 + j) * OW + ox0]     = acc[o * 4 + j * 2];
            if (ox0 + 1 < OW) ob[(oc * OH + oy0 + j) * OW + ox0 + 1] = acc[o * 4 + j * 2 + 1];
          }
        }
      }
    }
  }
  __syncthreads();
  if (tid < 20) atomicAdd(&stats[tid], sstat[tid]);
}

// ---------------- MFMA conv, square tile (conv3..conv7) ----------------
// Block = 1 image, 256 threads = 4 waves. LDS tile [row][col][ci] bf16 with
// BN+ReLU of previous layer fused on staging. Implicit GEMM:
// C[oc48, npix] = W[48, NC*32] x P; k-chunk quad q -> (tap, ci-group) so a
// B-frag is one ds_read_b128 at the shifted window.
template<int KS, int NC, int GMAX, int TD, int H, int PAD, int NPIX, int NSW>
__global__ __launch_bounds__(256) void conv_mfma_sq(
    const float* __restrict__ in, const __bf16* __restrict__ Wl,
    const float* __restrict__ pstats, const float* __restrict__ pgamma,
    const float* __restrict__ pbeta, float pinvn,
    float* __restrict__ out, float* __restrict__ stats) {
  constexpr int OWT = H + 2 * PAD - KS + 1;
  constexpr int NSUB = (NPIX + 15) / 16;
  static_assert(TD == H + 2 * PAD, "tile dim");
  __shared__ __bf16 tile[TD * TD * 40];
  __shared__ float sc[10], sh[10], sstat[20];
  const int tid = threadIdx.x;
  const int img = blockIdx.x;
  if (tid < 20) sstat[tid] = 0.f;
  if (tid >= 32 && tid < 42) {
    int f = tid - 32;
    float mu = pstats[f] * pinvn, q = pstats[10 + f] * pinvn;
    float isd = rsqrtf(q - mu * mu + EPSV);
    float s = pgamma[f] * isd;
    sc[f] = s; sh[f] = pbeta[f] - mu * s;
  }
  __syncthreads();

  // ---- staging: BN+ReLU(prev) -> bf16 -> LDS [row][col][ci] ----
  const float* ib = in + (long)img * (40 * H * H);
  if (tid < TD * TD) {
    const int iy = tid / TD, ix = tid % TD;
    const int gy = iy - PAD, gx = ix - PAD;
    const bool inb = (gy >= 0 && gy < H && gx >= 0 && gx < H);
    const int gofs = gy * H + gx;
#pragma unroll 4
    for (int ci = 0; ci < 40; ++ci) {
      float v = 0.f;
      if (inb) {
        v = ib[ci * (H * H) + gofs];
        v = fmaxf(0.f, fmaf(v, sc[ci >> 2], sh[ci >> 2]));
      }
      tile[tid * 40 + ci] = (__bf16)v;
    }
  }
  __syncthreads();

  const int lane = tid & 63, wv = tid >> 6;
  const int m = lane & 15, quad = lane >> 4;
  int pbase[NSW], nsv[NSW];
  bool sv[NSW], nva[NSW];
#pragma unroll
  for (int s = 0; s < NSW; ++s) {
    int ns = wv + 4 * s;
    sv[s] = ns < NSUB;
    int n = ns * 16 + m;
    nva[s] = sv[s] && (n < NPIX);
    n = n < NPIX ? n : NPIX - 1;
    nsv[s] = n;
    int y = n / OWT, x = n % OWT;
    pbase[s] = (y * TD + x) * 40;
  }
  v4f acc[3][NSW] = {};

  const __bf16* wlane = Wl + (quad * 16 + m) * 8;
  for (int c = 0; c < NC; ++c) {
    int g = 4 * c + quad; g = g > GMAX ? GMAX : g;
    int tap = g / 5, cig = g - tap * 5;
    int dy = tap / KS, dx = tap - dy * KS;
    int boff = (dy * TD + dx) * 40 + cig * 8;
    v8bf bfr[NSW];
#pragma unroll
    for (int s = 0; s < NSW; ++s)
      if (sv[s]) bfr[s] = *(const v8bf*)&tile[pbase[s] + boff];
    v8bf afr[3];
#pragma unroll
    for (int mt = 0; mt < 3; ++mt)
      afr[mt] = *(const v8bf*)(wlane + (mt * NC + c) * 512);
#pragma unroll
    for (int s = 0; s < NSW; ++s)
      if (sv[s]) {
#pragma unroll
        for (int mt = 0; mt < 3; ++mt)
          acc[mt][s] = __builtin_amdgcn_mfma_f32_16x16x32_bf16(afr[mt], bfr[s],
                                                              acc[mt][s], 0, 0, 0);
      }
  }

  // ---- BN stats: field = mt*4 + quad (constant per lane & mt) ----
#pragma unroll
  for (int mt = 0; mt < 3; ++mt) {
    float svv = 0.f, qvv = 0.f;
#pragma unroll
    for (int s = 0; s < NSW; ++s)
      if (nva[s]) {
#pragma unroll
        for (int r = 0; r < 4; ++r) { float v = acc[mt][s][r]; svv += v; qvv += v * v; }
      }
    const bool ocok = (mt < 2) || (quad < 2);
#pragma unroll
    for (int off = 1; off <= 8; off <<= 1) {
      svv += __shfl_xor(svv, off, 64);
      qvv += __shfl_xor(qvv, off, 64);
    }
    if (m == 0 && ocok) {
      atomicAdd(&sstat[mt * 4 + quad], svv);
      atomicAdd(&sstat[10 + mt * 4 + quad], qvv);
    }
  }

  // ---- store raw fp32 ----
  float* ob = out + (long)img * (40 * NPIX);
#pragma unroll
  for (int mt = 0; mt < 3; ++mt) {
    const bool ocok = (mt < 2) || (quad < 2);
    const int oc0 = mt * 16 + quad * 4;
#pragma unroll
    for (int s = 0; s < NSW; ++s)
      if (ocok && nva[s]) {
#pragma unroll
        for (int r = 0; r < 4; ++r) ob[(oc0 + r) * NPIX + nsv[s]] = acc[mt][s][r];
      }
  }
  __syncthreads();
  if (tid < 20) atomicAdd(&stats[tid], sstat[tid]);
}

// ---------------- MFMA conv2: row-band + fused 2x2 maxpool ----------------
// Band of R rows x 28 cols of one image. Full-res stats; raw outputs pooled
// through LDS (bf16) before global write (gamma>0 -> BN/pool commute).
template<int R>
__global__ __launch_bounds__(256) void conv_mfma_band(
    const float* __restrict__ in, const __bf16* __restrict__ Wl,
    const float* __restrict__ pstats, const float* __restrict__ pgamma,
    const float* __restrict__ pbeta, float pinvn,
    float* __restrict__ outp, float* __restrict__ stats) {
  constexpr int NPIX = R * 28, NSUB = NPIX / 16, NSW = (NSUB + 3) / 4;
  constexpr int SROWS = R + 2, SCNT = 40 * SROWS * 30;
  __shared__ __bf16 tile[SROWS * 30 * 40];
  __shared__ float sc[10], sh[10], sstat[20];
  const int tid = threadIdx.x;
  int img, y0;
  if constexpr (R == 8) { img = blockIdx.x / 3; y0 = (blockIdx.x % 3) * 8; }
  else { img = blockIdx.x; y0 = 24; }

  if (tid < 20) sstat[tid] = 0.f;
  if (tid >= 32 && tid < 42) {
    int f = tid - 32;
    float mu = pstats[f] * pinvn, q = pstats[10 + f] * pinvn;
    float isd = rsqrtf(q - mu * mu + EPSV);
    float s = pgamma[f] * isd;
    sc[f] = s; sh[f] = pgamma[f] * 0.f + pbeta[f] - mu * s;
  }
  __syncthreads();

  for (int idx = tid; idx < SCNT; idx += 256) {
    int ci = idx / (SROWS * 30), rem = idx % (SROWS * 30);
    int iy = rem / 30, ix = rem % 30;
    int gy = y0 + iy - 1, gx = ix - 1;
    float v = 0.f;
    if (gy >= 0 && gy < 28 && gx >= 0 && gx < 28) {
      v = in[((long)img * 40 + ci) * 784 + gy * 28 + gx];
      v = fmaxf(0.f, fmaf(v, sc[ci >> 2], sh[ci >> 2]));
    }
    tile[(iy * 30 + ix) * 40 + ci] = (__bf16)v;
  }
  __syncthreads();

  const int lane = tid & 63, wv = tid >> 6;
  const int m = lane & 15, quad = lane >> 4;
  int pbase[NSW], nsv[NSW];
  bool sv[NSW];
#pragma unroll
  for (int s = 0; s < NSW; ++s) {
    int ns = wv + 4 * s;
    sv[s] = ns < NSUB;
    int n = ns * 16 + m;
    n = n < NPIX ? n : NPIX - 1;
    nsv[s] = n;
    int y = n / 28, x = n % 28;
    pbase[s] = (y * 30 + x) * 40;
  }
  v4f acc[3][NSW] = {};

  const __bf16* wlane = Wl + (quad * 16 + m) * 8;
  for (int c = 0; c < 12; ++c) {
    int g = 4 * c + quad; g = g > 44 ? 44 : g;
    int tap = g / 5, cig = g - tap * 5;
    int dy = tap / 3, dx = tap - dy * 3;
    int boff = (dy * 30 + dx) * 40 + cig * 8;
    v8bf bfr[NSW];
#pragma unroll
    for (int s = 0; s < NSW; ++s)
      if (sv[s]) bfr[s] = *(const v8bf*)&tile[pbase[s] + boff];
    v8bf afr[3];
#pragma unroll
    for (int mt = 0; mt < 3; ++mt)
      afr[mt] = *(const v8bf*)(wlane + (mt * 12 + c) * 512);
#pragma unroll
    for (int s = 0; s < NSW; ++s)
      if (sv[s]) {
#pragma unroll
        for (int mt = 0; mt < 3; ++mt)
          acc[mt][s] = __builtin_amdgcn_mfma_f32_16x16x32_bf16(afr[mt], bfr[s],
                                                              acc[mt][s], 0, 0, 0);
      }
  }

  // ---- full-res BN stats ----
#pragma unroll
  for (int mt = 0; mt < 3; ++mt) {
    float svv = 0.f, qvv = 0.f;
#pragma unroll
    for (int s = 0; s < NSW; ++s)
      if (sv[s]) {
#pragma unroll
        for (int r = 0; r < 4; ++r) { float v = acc[mt][s][r]; svv += v; qvv += v * v; }
      }
    const bool ocok = (mt < 2) || (quad < 2);
#pragma unroll
    for (int off = 1; off <= 8; off <<= 1) {
      svv += __shfl_xor(svv, off, 64);
      qvv += __shfl_xor(qvv, off, 64);
    }
    if (m == 0 && ocok) {
      atomicAdd(&sstat[mt * 4 + quad], svv);
      atomicAdd(&sstat[10 + mt * 4 + quad], qvv);
    }
  }

  // ---- raw band -> LDS (bf16, reuse tile) -> 2x2 maxpool -> global ----
  __syncthreads();                 // all tile reads done
  __bf16* pool = tile;             // 40*NPIX <= SROWS*30*40
#pragma unroll
  for (int mt = 0; mt < 3; ++mt) {
    const bool ocok = (mt < 2) || (quad < 2);
    const int oc0 = mt * 16 + quad * 4;
#pragma unroll
    for (int s = 0; s < NSW; ++s)
      if (ocok && sv[s]) {
#pragma unroll
        for (int r = 0; r < 4; ++r)
          pool[(oc0 + r) * NPIX + nsv[s]] = (__bf16)acc[mt][s][r];
      }
  }
  __syncthreads();
  constexpr int PR = R / 2, PCNT = 40 * PR * 14;
  for (int i = tid; i < PCNT; i += 256) {
    int oc = i / (PR * 14), rem = i % (PR * 14);
    int py = rem / 14, px = rem % 14;
    const __bf16* pp = pool + oc * NPIX + py * 56 + px * 2;
    float a = (float)pp[0], b = (float)pp[1], c = (float)pp[28], d = (float)pp[29];
    outp[((long)img * 40 + oc) * 196 + (y0 / 2 + py) * 14 + px] =
        fmaxf(fmaxf(a, b), fmaxf(c, d));
  }
  if (tid < 20) atomicAdd(&stats[tid], sstat[tid]);
}

// BN+ReLU(layer7) -> orientation max -> FC. One block per image.
__global__ __launch_bounds__(256) void head_kernel(
    const float* __restrict__ raw, const float* __restrict__ stats7,
    const float* __restrict__ gs, const float* __restrict__ bs,
    const float* __restrict__ wfc, const float* __restrict__ bfc,
    float* __restrict__ out, float invn) {
  __shared__ float sc[10], sh[10];
  __shared__ float mbuf[1210];
  __shared__ float red[40];
  const int tid = threadIdx.x, n = blockIdx.x;
  if (tid < 10) {
    float mu = stats7[tid] * invn, q = stats7[10 + tid] * invn;
    float isd = rsqrtf(q - mu * mu + EPSV);
    float s = gs[tid] * isd;
    sc[tid] = s;
    sh[tid] = bs[tid] - mu * s;
  }
  __syncthreads();
  const float* rb = raw + (long)n * 40 * 121;
  for (int idx = tid; idx < 1210; idx += blockDim.x) {
    int c = idx / 121, p = idx % 121;
    float s = sc[c], h = sh[c];
    float v0 = fmaxf(0.f, fmaf(rb[(c * 4 + 0) * 121 + p], s, h));
    float v1 = fmaxf(0.f, fmaf(rb[(c * 4 + 1) * 121 + p], s, h));
    float v2 = fmaxf(0.f, fmaf(rb[(c * 4 + 2) * 121 + p], s, h));
    float v3 = fmaxf(0.f, fmaf(rb[(c * 4 + 3) * 121 + p], s, h));
    mbuf[idx] = fmaxf(fmaxf(v0, v1), fmaxf(v2, v3));
  }
  __syncthreads();
  const int wv = tid >> 6, lane = tid & 63;
  for (int k = 0; k < 10; ++k) {
    float p = 0.f;
    for (int j = tid; j < 1210; j += blockDim.x) p += mbuf[j] * wfc[k * 1210 + j];
#pragma unroll
    for (int off = 32; off > 0; off >>= 1) p += __shfl_xor(p, off, 64);
    if (lane == 0) red[k * 4 + wv] = p;
  }
  __syncthreads();
  if (tid < 10)
    out[n * 10 + tid] = bfc[tid] + red[tid * 4] + red[tid * 4 + 1] +
                        red[tid * 4 + 2] + red[tid * 4 + 3];
}

extern "C" void kernel_launch(void* const* d_in, const int* in_sizes, int n_in,
                              void* d_out, int out_size, void* d_ws, size_t ws_size,
                              hipStream_t stream) {
  const float* x   = (const float*)d_in[0];
  const float* w1  = (const float*)d_in[1];
  const float* w2  = (const float*)d_in[2];
  const float* w3  = (const float*)d_in[3];
  const float* w4  = (const float*)d_in[4];
  const float* w5  = (const float*)d_in[5];
  const float* w6  = (const float*)d_in[6];
  const float* w7  = (const float*)d_in[7];
  const float* g1  = (const float*)d_in[8];
  const float* b1  = (const float*)d_in[9];
  const float* g2  = (const float*)d_in[10];
  const float* b2  = (const float*)d_in[11];
  const float* gs  = (const float*)d_in[12];
  const float* bs  = (const float*)d_in[13];
  const float* wfc = (const float*)d_in[14];
  const float* bfc = (const float*)d_in[15];

  float* ws = (float*)d_ws;
  // Workspace (floats), total ~160.8 MB:
  float* A     = ws;                  // conv1 raw [1024,40,28,28] (32,112,640)
  float* B14   = ws + 32112640L;      // pooled conv2 raw [1024,40,14,14]
  float* C14   = ws;                  // ping (A dead after conv2)
  float* D14   = ws + 8028160L;       // pong
  float* B11   = B14;                 // conv7 raw (B14 dead after conv3)
  float* K1    = ws + 40140800L;      // conv1 table, 360 floats
  float* stats = ws + 40141160L;      // 7 x 32 floats
  __bf16* Wb   = (__bf16*)(ws + 40141384L); // 122,880 bf16 MFMA tables

  const float invn28 = 1.f / 3211264.f;
  const float invn14 = 1.f / 802816.f;
  const float invn11 = 1.f / 495616.f;

  prep_kernel<<<483, 256, 0, stream>>>(w1, w2, w3, w4, w5, w6, w7, K1, Wb, stats);

  // conv1 (lift, Cin=1, fp32): raw -> A, stats[0]
  convk2<1, 28, 28, 28, 28, 3, 1, 2, 2, 7, 7, false, false, 256>
      <<<4096, 256, 0, stream>>>(x, K1, nullptr, nullptr, nullptr, 0.f, A, stats);
  // conv2 (MFMA bands): BN1 in, full-res stats[1], pooled raw -> B14
  conv_mfma_band<8><<<3072, 256, 0, stream>>>(A, Wb, stats, g1, b1, invn28,
                                              B14, stats + 32);
  conv_mfma_band<4><<<1024, 256, 0, stream>>>(A, Wb, stats, g1, b1, invn28,
                                              B14, stats + 32);
  // conv3..conv6 (MFMA, 14x14)
  conv_mfma_sq<3, 12, 44, 16, 14, 1, 196, 4><<<1024, 256, 0, stream>>>(
      B14, Wb + 18432, stats + 32, g2, b2, invn28, C14, stats + 64);
  conv_mfma_sq<3, 12, 44, 16, 14, 1, 196, 4><<<1024, 256, 0, stream>>>(
      C14, Wb + 36864, stats + 64, gs, bs, invn14, D14, stats + 96);
  conv_mfma_sq<3, 12, 44, 16, 14, 1, 196, 4><<<1024, 256, 0, stream>>>(
      D14, Wb + 55296, stats + 96, gs, bs, invn14, C14, stats + 128);
  conv_mfma_sq<3, 12, 44, 16, 14, 1, 196, 4><<<1024, 256, 0, stream>>>(
      C14, Wb + 73728, stats + 128, gs, bs, invn14, D14, stats + 160);
  // conv7 (MFMA, 4x4 valid, 14->11)
  conv_mfma_sq<4, 20, 79, 14, 14, 0, 121, 2><<<1024, 256, 0, stream>>>(
      D14, Wb + 92160, stats + 160, gs, bs, invn14, B11, stats + 192);
  // head
  head_kernel<<<1024, 256, 0, stream>>>(B11, stats + 192, gs, bs, wfc, bfc,
                                        (float*)d_out, invn11);
}

// Round 4
// 355.553 us; speedup vs baseline: 8.7314x; 2.0005x over previous
//
#include <hip/hip_runtime.h>

#define EPSV 1e-5f

typedef __bf16 v8bf __attribute__((ext_vector_type(8)));
typedef float v4f __attribute__((ext_vector_type(4)));

// rot90 applied r times CCW (np.rot90 semantics): out[dy][dx] = m[sy][sx]
__device__ __forceinline__ int rotsrc(int r, int dy, int dx, int K) {
  int sy, sx;
  if (r == 0)      { sy = dy;       sx = dx; }
  else if (r == 1) { sy = dx;       sx = K - 1 - dy; }
  else if (r == 2) { sy = K - 1 - dy; sx = K - 1 - dx; }
  else             { sy = K - 1 - dx; sx = dy; }
  return sy * K + sx;
}

// P4 weight expansion: full kernel value for output channel oc, k-group g,
// within-group index j. g = (tap, ci-group-of-8): tap = g/5, ci = (g%5)*8+j.
__device__ __forceinline__ float gw_val(const float* __restrict__ w, int oc, int g,
                                        int j, int KS) {
  int tap = g / 5, cig = g % 5, ci = cig * 8 + j;
  int co = oc >> 2, r = oc & 3, cin = ci >> 2, s = ci & 3;
  int srel = (s - r) & 3;
  return w[((co * 10 + cin) * 4 + srel) * (KS * KS) + rotsrc(r, tap / KS, tap % KS, KS)];
}

// Zero stats (7 layers x 8 copies x 32) + conv1 table [tap][oc] + MFMA bf16
// weight tables [mt(3)][c(NC)][q(4)][ocl(16)][j(8)].
__global__ void prep_kernel(const float* __restrict__ w1, const float* __restrict__ w2,
                            const float* __restrict__ w3, const float* __restrict__ w4,
                            const float* __restrict__ w5, const float* __restrict__ w6,
                            const float* __restrict__ w7,
                            float* __restrict__ K1, __bf16* __restrict__ Wb,
                            float* __restrict__ stats) {
  int idx = blockIdx.x * blockDim.x + threadIdx.x;
  if (idx < 1792) { stats[idx] = 0.f; return; }
  idx -= 1792;
  if (idx < 360) { // lifting kernel [tap][oc]
    int tap = idx / 40, oc = idx % 40;
    int c = oc >> 2, r = oc & 3;
    K1[idx] = w1[c * 9 + rotsrc(r, tap / 3, tap % 3, 3)];
    return;
  }
  idx -= 360;
  if (idx < 92160) { // conv2..conv6: 5 layers x [3][12][4][16][8]
    int l = idx / 18432, r0 = idx % 18432;
    const float* w = (l == 0) ? w2 : (l == 1) ? w3 : (l == 2) ? w4 : (l == 3) ? w5 : w6;
    int mt = r0 / 6144, r1 = r0 % 6144;
    int c = r1 / 512, r2 = r1 % 512;
    int q = r2 / 128, r3 = r2 % 128;
    int ocl = r3 / 8, j = r3 % 8;
    int oc = mt * 16 + ocl, g = c * 4 + q;
    float val = 0.f;
    if (oc < 40 && g < 45) val = gw_val(w, oc, g, j, 3);
    Wb[idx] = (__bf16)val;
    return;
  }
  idx -= 92160;
  if (idx < 30720) { // conv7: [3][20][4][16][8]
    int mt = idx / 10240, r1 = idx % 10240;
    int c = r1 / 512, r2 = r1 % 512;
    int q = r2 / 128, r3 = r2 % 128;
    int ocl = r3 / 8, j = r3 % 8;
    int oc = mt * 16 + ocl, g = c * 4 + q;
    float val = 0.f;
    if (oc < 40) val = gw_val(w7, oc, g, j, 4);
    Wb[92160 + idx] = (__bf16)val;
  }
}

// ---------------- conv1 stats only (no activation materialized) ----------------
// One block per image: stage 30x30 zero-padded x + w1 table in LDS, each thread
// computes conv1 for ~3 pixels x 40 oc, reduces per-field sum/sumsq.
__global__ __launch_bounds__(256) void conv1_stats(
    const float* __restrict__ x, const float* __restrict__ K1,
    float* __restrict__ stats) {
  __shared__ float ximg[900];
  __shared__ float wk[360];
  __shared__ float sstat[20];
  const int tid = threadIdx.x, img = blockIdx.x;
  if (tid < 20) sstat[tid] = 0.f;
  for (int i = tid; i < 900; i += 256) {
    int gy = i / 30 - 1, gx = i % 30 - 1;
    ximg[i] = (gy >= 0 && gy < 28 && gx >= 0 && gx < 28)
                  ? x[img * 784 + gy * 28 + gx] : 0.f;
  }
  for (int i = tid; i < 360; i += 256) wk[i] = K1[i];
  __syncthreads();

  float s[10], q[10];
#pragma unroll
  for (int f = 0; f < 10; ++f) { s[f] = 0.f; q[f] = 0.f; }
  for (int p = tid; p < 784; p += 256) {
    const int y = p / 28, xx = p % 28;
    float patch[9];
#pragma unroll
    for (int t = 0; t < 9; ++t) patch[t] = ximg[(y + t / 3) * 30 + xx + t % 3];
#pragma unroll
    for (int f = 0; f < 10; ++f) {
#pragma unroll
      for (int r = 0; r < 4; ++r) {
        const int oc = f * 4 + r;
        float v = 0.f;
#pragma unroll
        for (int t = 0; t < 9; ++t) v = fmaf(patch[t], wk[t * 40 + oc], v);
        s[f] += v; q[f] += v * v;
      }
    }
  }
#pragma unroll
  for (int f = 0; f < 10; ++f) {
#pragma unroll
    for (int off = 1; off <= 32; off <<= 1) {
      s[f] += __shfl_xor(s[f], off, 64);
      q[f] += __shfl_xor(q[f], off, 64);
    }
  }
  if ((tid & 63) == 0) {
#pragma unroll
    for (int f = 0; f < 10; ++f) {
      atomicAdd(&sstat[f], s[f]);
      atomicAdd(&sstat[10 + f], q[f]);
    }
  }
  __syncthreads();
  if (tid < 20) atomicAdd(&stats[(img & 7) * 32 + tid], sstat[tid]);
}

// sum 8 shadow copies of a stat slot
__device__ __forceinline__ float stat8(const float* __restrict__ p, int i) {
  float v = 0.f;
#pragma unroll
  for (int c = 0; c < 8; ++c) v += p[c * 32 + i];
  return v;
}

// ---------------- MFMA conv, square tile (conv3..conv7) ----------------
template<int KS, int NC, int GMAX, int TD, int H, int PAD, int NPIX, int NSW>
__global__ __launch_bounds__(256) void conv_mfma_sq(
    const float* __restrict__ in, const __bf16* __restrict__ Wl,
    const float* __restrict__ pstats, const float* __restrict__ pgamma,
    const float* __restrict__ pbeta, float pinvn,
    float* __restrict__ out, float* __restrict__ stats) {
  constexpr int OWT = H + 2 * PAD - KS + 1;
  constexpr int NSUB = (NPIX + 15) / 16;
  static_assert(TD == H + 2 * PAD, "tile dim");
  __shared__ __bf16 tile[TD * TD * 40];
  __shared__ float sc[10], sh[10], sstat[20];
  const int tid = threadIdx.x;
  const int img = blockIdx.x;
  if (tid < 20) sstat[tid] = 0.f;
  if (tid >= 32 && tid < 42) {
    int f = tid - 32;
    float mu = stat8(pstats, f) * pinvn, q = stat8(pstats, 10 + f) * pinvn;
    float isd = rsqrtf(q - mu * mu + EPSV);
    float s = pgamma[f] * isd;
    sc[f] = s; sh[f] = pbeta[f] - mu * s;
  }
  __syncthreads();

  const float* ib = in + (long)img * (40 * H * H);
  if (tid < TD * TD) {
    const int iy = tid / TD, ix = tid % TD;
    const int gy = iy - PAD, gx = ix - PAD;
    const bool inb = (gy >= 0 && gy < H && gx >= 0 && gx < H);
    const int gofs = gy * H + gx;
#pragma unroll 4
    for (int ci = 0; ci < 40; ++ci) {
      float v = 0.f;
      if (inb) {
        v = ib[ci * (H * H) + gofs];
        v = fmaxf(0.f, fmaf(v, sc[ci >> 2], sh[ci >> 2]));
      }
      tile[tid * 40 + ci] = (__bf16)v;
    }
  }
  __syncthreads();

  const int lane = tid & 63, wv = tid >> 6;
  const int m = lane & 15, quad = lane >> 4;
  int pbase[NSW], nsv[NSW];
  bool sv[NSW], nva[NSW];
#pragma unroll
  for (int s = 0; s < NSW; ++s) {
    int ns = wv + 4 * s;
    sv[s] = ns < NSUB;
    int n = ns * 16 + m;
    nva[s] = sv[s] && (n < NPIX);
    n = n < NPIX ? n : NPIX - 1;
    nsv[s] = n;
    int y = n / OWT, x = n % OWT;
    pbase[s] = (y * TD + x) * 40;
  }
  v4f acc[3][NSW] = {};

  const __bf16* wlane = Wl + (quad * 16 + m) * 8;
  for (int c = 0; c < NC; ++c) {
    int g = 4 * c + quad; g = g > GMAX ? GMAX : g;
    int tap = g / 5, cig = g - tap * 5;
    int dy = tap / KS, dx = tap - dy * KS;
    int boff = (dy * TD + dx) * 40 + cig * 8;
    v8bf bfr[NSW];
#pragma unroll
    for (int s = 0; s < NSW; ++s)
      if (sv[s]) bfr[s] = *(const v8bf*)&tile[pbase[s] + boff];
    v8bf afr[3];
#pragma unroll
    for (int mt = 0; mt < 3; ++mt)
      afr[mt] = *(const v8bf*)(wlane + (mt * NC + c) * 512);
#pragma unroll
    for (int s = 0; s < NSW; ++s)
      if (sv[s]) {
#pragma unroll
        for (int mt = 0; mt < 3; ++mt)
          acc[mt][s] = __builtin_amdgcn_mfma_f32_16x16x32_bf16(afr[mt], bfr[s],
                                                              acc[mt][s], 0, 0, 0);
      }
  }

#pragma unroll
  for (int mt = 0; mt < 3; ++mt) {
    float svv = 0.f, qvv = 0.f;
#pragma unroll
    for (int s = 0; s < NSW; ++s)
      if (nva[s]) {
#pragma unroll
        for (int r = 0; r < 4; ++r) { float v = acc[mt][s][r]; svv += v; qvv += v * v; }
      }
    const bool ocok = (mt < 2) || (quad < 2);
#pragma unroll
    for (int off = 1; off <= 8; off <<= 1) {
      svv += __shfl_xor(svv, off, 64);
      qvv += __shfl_xor(qvv, off, 64);
    }
    if (m == 0 && ocok) {
      atomicAdd(&sstat[mt * 4 + quad], svv);
      atomicAdd(&sstat[10 + mt * 4 + quad], qvv);
    }
  }

  float* ob = out + (long)img * (40 * NPIX);
#pragma unroll
  for (int mt = 0; mt < 3; ++mt) {
    const bool ocok = (mt < 2) || (quad < 2);
    const int oc0 = mt * 16 + quad * 4;
#pragma unroll
    for (int s = 0; s < NSW; ++s)
      if (ocok && nva[s]) {
#pragma unroll
        for (int r = 0; r < 4; ++r) ob[(oc0 + r) * NPIX + nsv[s]] = acc[mt][s][r];
      }
  }
  __syncthreads();
  if (tid < 20) atomicAdd(&stats[(img & 7) * 32 + tid], sstat[tid]);
}

// ---------------- MFMA conv2 band with FUSED conv1 recompute ----------------
// Stages raw x patch (12x32) + w1 table; computes conv1 in fp32 on the fly,
// BN1+ReLU -> bf16 LDS tile. Full-res stats; raw outputs pooled through LDS.
template<int R>
__global__ __launch_bounds__(256) void conv_band_fused(
    const float* __restrict__ x, const float* __restrict__ K1,
    const __bf16* __restrict__ Wl, const float* __restrict__ pstats,
    const float* __restrict__ pgamma, const float* __restrict__ pbeta,
    float pinvn, float* __restrict__ outp, float* __restrict__ stats) {
  constexpr int NPIX = R * 28, NSUB = NPIX / 16, NSW = (NSUB + 3) / 4;
  constexpr int SROWS = R + 2, XR = R + 4;
  __shared__ __bf16 tile[SROWS * 30 * 40];
  __shared__ float xpatch[XR * 32];
  __shared__ float wk[360];
  __shared__ float sc[10], sh[10], sstat[20];
  const int tid = threadIdx.x;
  int img, y0;
  if constexpr (R == 8) { img = blockIdx.x / 3; y0 = (blockIdx.x % 3) * 8; }
  else { img = blockIdx.x; y0 = 24; }

  if (tid < 20) sstat[tid] = 0.f;
  if (tid >= 32 && tid < 42) {
    int f = tid - 32;
    float mu = stat8(pstats, f) * pinvn, q = stat8(pstats, 10 + f) * pinvn;
    float isd = rsqrtf(q - mu * mu + EPSV);
    float s = pgamma[f] * isd;
    sc[f] = s; sh[f] = pbeta[f] - mu * s;
  }
  for (int i = tid; i < XR * 32; i += 256) {
    int gy = y0 - 2 + i / 32, gx = i % 32 - 2;
    xpatch[i] = (gy >= 0 && gy < 28 && gx >= 0 && gx < 28)
                    ? x[(long)img * 784 + gy * 28 + gx] : 0.f;
  }
  for (int i = tid; i < 360; i += 256) wk[i] = K1[i];
  __syncthreads();

  // ---- staging: conv1 (fp32) -> BN1+ReLU -> bf16 tile [pix][ci] ----
  for (int p = tid; p < SROWS * 30; p += 256) {
    const int iy = p / 30, ix = p % 30;
    const int gy = y0 + iy - 1, gx = ix - 1;
    const bool inb = (gy >= 0 && gy < 28 && gx >= 0 && gx < 28);
    float patch[9];
#pragma unroll
    for (int t = 0; t < 9; ++t)
      patch[t] = xpatch[(iy + t / 3) * 32 + ix + t % 3];
    __bf16* tb = &tile[p * 40];
    if (inb) {
#pragma unroll 8
      for (int ci = 0; ci < 40; ++ci) {
        float v = 0.f;
#pragma unroll
        for (int t = 0; t < 9; ++t) v = fmaf(patch[t], wk[t * 40 + ci], v);
        v = fmaxf(0.f, fmaf(v, sc[ci >> 2], sh[ci >> 2]));
        tb[ci] = (__bf16)v;
      }
    } else {
#pragma unroll 8
      for (int ci = 0; ci < 40; ++ci) tb[ci] = (__bf16)0.f;
    }
  }
  __syncthreads();

  const int lane = tid & 63, wv = tid >> 6;
  const int m = lane & 15, quad = lane >> 4;
  int pbase[NSW], nsv[NSW];
  bool sv[NSW];
#pragma unroll
  for (int s = 0; s < NSW; ++s) {
    int ns = wv + 4 * s;
    sv[s] = ns < NSUB;
    int n = ns * 16 + m;
    n = n < NPIX ? n : NPIX - 1;
    nsv[s] = n;
    int y = n / 28, xx = n % 28;
    pbase[s] = (y * 30 + xx) * 40;
  }
  v4f acc[3][NSW] = {};

  const __bf16* wlane = Wl + (quad * 16 + m) * 8;
  for (int c = 0; c < 12; ++c) {
    int g = 4 * c + quad; g = g > 44 ? 44 : g;
    int tap = g / 5, cig = g - tap * 5;
    int dy = tap / 3, dx = tap - dy * 3;
    int boff = (dy * 30 + dx) * 40 + cig * 8;
    v8bf bfr[NSW];
#pragma unroll
    for (int s = 0; s < NSW; ++s)
      if (sv[s]) bfr[s] = *(const v8bf*)&tile[pbase[s] + boff];
    v8bf afr[3];
#pragma unroll
    for (int mt = 0; mt < 3; ++mt)
      afr[mt] = *(const v8bf*)(wlane + (mt * 12 + c) * 512);
#pragma unroll
    for (int s = 0; s < NSW; ++s)
      if (sv[s]) {
#pragma unroll
        for (int mt = 0; mt < 3; ++mt)
          acc[mt][s] = __builtin_amdgcn_mfma_f32_16x16x32_bf16(afr[mt], bfr[s],
                                                              acc[mt][s], 0, 0, 0);
      }
  }

#pragma unroll
  for (int mt = 0; mt < 3; ++mt) {
    float svv = 0.f, qvv = 0.f;
#pragma unroll
    for (int s = 0; s < NSW; ++s)
      if (sv[s]) {
#pragma unroll
        for (int r = 0; r < 4; ++r) { float v = acc[mt][s][r]; svv += v; qvv += v * v; }
      }
    const bool ocok = (mt < 2) || (quad < 2);
#pragma unroll
    for (int off = 1; off <= 8; off <<= 1) {
      svv += __shfl_xor(svv, off, 64);
      qvv += __shfl_xor(qvv, off, 64);
    }
    if (m == 0 && ocok) {
      atomicAdd(&sstat[mt * 4 + quad], svv);
      atomicAdd(&sstat[10 + mt * 4 + quad], qvv);
    }
  }

  // ---- raw band -> LDS (bf16) -> 2x2 maxpool -> global ----
  __syncthreads();
  __bf16* pool = tile;
#pragma unroll
  for (int mt = 0; mt < 3; ++mt) {
    const bool ocok = (mt < 2) || (quad < 2);
    const int oc0 = mt * 16 + quad * 4;
#pragma unroll
    for (int s = 0; s < NSW; ++s)
      if (ocok && sv[s]) {
#pragma unroll
        for (int r = 0; r < 4; ++r)
          pool[(oc0 + r) * NPIX + nsv[s]] = (__bf16)acc[mt][s][r];
      }
  }
  __syncthreads();
  constexpr int PR = R / 2, PCNT = 40 * PR * 14;
  for (int i = tid; i < PCNT; i += 256) {
    int oc = i / (PR * 14), rem = i % (PR * 14);
    int py = rem / 14, px = rem % 14;
    const __bf16* pp = pool + oc * NPIX + py * 56 + px * 2;
    float a = (float)pp[0], b = (float)pp[1], c = (float)pp[28], d = (float)pp[29];
    outp[((long)img * 40 + oc) * 196 + (y0 / 2 + py) * 14 + px] =
        fmaxf(fmaxf(a, b), fmaxf(c, d));
  }
  if (tid < 20) atomicAdd(&stats[(img & 7) * 32 + tid], sstat[tid]);
}

// BN+ReLU(layer7) -> orientation max -> FC. One block per image.
__global__ __launch_bounds__(256) void head_kernel(
    const float* __restrict__ raw, const float* __restrict__ stats7,
    const float* __restrict__ gs, const float* __restrict__ bs,
    const float* __restrict__ wfc, const float* __restrict__ bfc,
    float* __restrict__ out, float invn) {
  __shared__ float sc[10], sh[10];
  __shared__ float mbuf[1210];
  __shared__ float red[40];
  const int tid = threadIdx.x, n = blockIdx.x;
  if (tid < 10) {
    float mu = stat8(stats7, tid) * invn, q = stat8(stats7, 10 + tid) * invn;
    float isd = rsqrtf(q - mu * mu + EPSV);
    float s = gs[tid] * isd;
    sc[tid] = s;
    sh[tid] = bs[tid] - mu * s;
  }
  __syncthreads();
  const float* rb = raw + (long)n * 40 * 121;
  for (int idx = tid; idx < 1210; idx += blockDim.x) {
    int c = idx / 121, p = idx % 121;
    float s = sc[c], h = sh[c];
    float v0 = fmaxf(0.f, fmaf(rb[(c * 4 + 0) * 121 + p], s, h));
    float v1 = fmaxf(0.f, fmaf(rb[(c * 4 + 1) * 121 + p], s, h));
    float v2 = fmaxf(0.f, fmaf(rb[(c * 4 + 2) * 121 + p], s, h));
    float v3 = fmaxf(0.f, fmaf(rb[(c * 4 + 3) * 121 + p], s, h));
    mbuf[idx] = fmaxf(fmaxf(v0, v1), fmaxf(v2, v3));
  }
  __syncthreads();
  const int wv = tid >> 6, lane = tid & 63;
  for (int k = 0; k < 10; ++k) {
    float p = 0.f;
    for (int j = tid; j < 1210; j += blockDim.x) p += mbuf[j] * wfc[k * 1210 + j];
#pragma unroll
    for (int off = 32; off > 0; off >>= 1) p += __shfl_xor(p, off, 64);
    if (lane == 0) red[k * 4 + wv] = p;
  }
  __syncthreads();
  if (tid < 10)
    out[n * 10 + tid] = bfc[tid] + red[tid * 4] + red[tid * 4 + 1] +
                        red[tid * 4 + 2] + red[tid * 4 + 3];
}

extern "C" void kernel_launch(void* const* d_in, const int* in_sizes, int n_in,
                              void* d_out, int out_size, void* d_ws, size_t ws_size,
                              hipStream_t stream) {
  const float* x   = (const float*)d_in[0];
  const float* w1  = (const float*)d_in[1];
  const float* w2  = (const float*)d_in[2];
  const float* w3  = (const float*)d_in[3];
  const float* w4  = (const float*)d_in[4];
  const float* w5  = (const float*)d_in[5];
  const float* w6  = (const float*)d_in[6];
  const float* w7  = (const float*)d_in[7];
  const float* g1  = (const float*)d_in[8];
  const float* b1  = (const float*)d_in[9];
  const float* g2  = (const float*)d_in[10];
  const float* b2  = (const float*)d_in[11];
  const float* gs  = (const float*)d_in[12];
  const float* bs  = (const float*)d_in[13];
  const float* wfc = (const float*)d_in[14];
  const float* bfc = (const float*)d_in[15];

  float* ws = (float*)d_ws;
  // Workspace (floats):
  float* C14   = ws;                  // ping [1024,40,14,14] (8,028,160)
  float* D14   = ws + 8028160L;       // pong
  float* B14   = ws + 32112640L;      // pooled conv2 raw [1024,40,14,14]
  float* B11   = B14;                 // conv7 raw (B14 dead after conv3)
  float* K1    = ws + 40140800L;      // conv1 table, 360 floats
  float* stats = ws + 40141160L;      // 7 layers x 8 copies x 32 floats = 1792
  __bf16* Wb   = (__bf16*)(ws + 40142952L); // 122,880 bf16 MFMA tables

  const float invn28 = 1.f / 3211264.f;
  const float invn14 = 1.f / 802816.f;
  const float invn11 = 1.f / 495616.f;

  prep_kernel<<<489, 256, 0, stream>>>(w1, w2, w3, w4, w5, w6, w7, K1, Wb, stats);

  // conv1: stats only (activation recomputed in conv2's staging)
  conv1_stats<<<1024, 256, 0, stream>>>(x, K1, stats);
  // conv2 (MFMA bands, conv1 fused): full-res stats[1], pooled raw -> B14
  conv_band_fused<8><<<3072, 256, 0, stream>>>(x, K1, Wb, stats, g1, b1, invn28,
                                               B14, stats + 256);
  conv_band_fused<4><<<1024, 256, 0, stream>>>(x, K1, Wb, stats, g1, b1, invn28,
                                               B14, stats + 256);
  // conv3..conv6 (MFMA, 14x14)
  conv_mfma_sq<3, 12, 44, 16, 14, 1, 196, 4><<<1024, 256, 0, stream>>>(
      B14, Wb + 18432, stats + 256, g2, b2, invn28, C14, stats + 512);
  conv_mfma_sq<3, 12, 44, 16, 14, 1, 196, 4><<<1024, 256, 0, stream>>>(
      C14, Wb + 36864, stats + 512, gs, bs, invn14, D14, stats + 768);
  conv_mfma_sq<3, 12, 44, 16, 14, 1, 196, 4><<<1024, 256, 0, stream>>>(
      D14, Wb + 55296, stats + 768, gs, bs, invn14, C14, stats + 1024);
  conv_mfma_sq<3, 12, 44, 16, 14, 1, 196, 4><<<1024, 256, 0, stream>>>(
      C14, Wb + 73728, stats + 1024, gs, bs, invn14, D14, stats + 1280);
  // conv7 (MFMA, 4x4 valid, 14->11)
  conv_mfma_sq<4, 20, 79, 14, 14, 0, 121, 2><<<1024, 256, 0, stream>>>(
      D14, Wb + 92160, stats + 1280, gs, bs, invn14, B11, stats + 1536);
  // head
  head_kernel<<<1024, 256, 0, stream>>>(B11, stats + 1536, gs, bs, wfc, bfc,
                                        (float*)d_out, invn11);
}